// Round 10
// baseline (998.371 us; speedup 1.0000x reference)
//
#include <hip/hip_runtime.h>
#include <stdint.h>

// FourierBlock: B=32, D=64, N=128, L=192, M=32 modes.
// ROUND 10 = fix + attribution. REP-banded kernels (r8 technique) so all three
// appear named in rocprof top-5 with counters. Per-iter = dispatch_dur / REP.
//   k1d: k1n + T14 async-split + double-buffered bf16 qS: next phase's 12
//        float4 loads issued BEFORE the MFMA cluster (96KB/block in flight
//        across compute), convert in stage path, XE stride 132 (bank fix).
//   k2h: r9 verbatim (i-split staging, 2 blk/CU) -- resolves r9 ambiguity.
//   k3:  r8 verbatim (measured at write-roofline ~30us).
// ws: Xp 33.5MB @0, Yp 33.5MB @16777216 u16.

typedef __attribute__((ext_vector_type(8))) short short8;
typedef __attribute__((ext_vector_type(4))) float f32x4;
typedef __attribute__((ext_vector_type(4))) unsigned short u16x4;

#define REP_K1 4
#define REP_K2 4
#define REP_K3 6

__device__ __forceinline__ unsigned short f2bf(float f) {
  union { float fv; uint32_t u; } v; v.fv = f;
  uint32_t u = v.u;
  u += 0x7fffu + ((u >> 16) & 1u);          // round-to-nearest-even
  return (unsigned short)(u >> 16);
}

__device__ __forceinline__ f32x4 zero4() { f32x4 z; z[0]=0.f; z[1]=0.f; z[2]=0.f; z[3]=0.f; return z; }

#define TWO_PI_OVER_L (6.283185307179586f / 192.0f)

// ---------------------------------------------------------------------------
// k1d: DFT, async double-buffered. grid 512 = (nq 32, bq 8, ih 2), 512 thr.
// LDS: qB0 [128][200]u16 @0 (51200), qB1 @51200, Fb [64][200] @102400 (25600),
//      XE [64 cat][132] @128000 (16896). Total 144896 B -> 1 blk/CU.
// Per phase: issue next loads -> MFMA(cur) -> cvt->nxt -> sync -> XE -> sync
// -> Xp stores. Loads in flight under MFMA+drain; HBM busy whole phase.
// ---------------------------------------------------------------------------
__global__ __launch_bounds__(512, 1)
void k1d_dft(const float* __restrict__ q, unsigned short* __restrict__ Xp) {
  extern __shared__ char smem[];
  unsigned short* qB0 = (unsigned short*)smem;
  unsigned short* qB1 = (unsigned short*)(smem + 51200);
  unsigned short* Fb  = (unsigned short*)(smem + 102400);
  unsigned short* XE  = (unsigned short*)(smem + 128000);
  const int t = threadIdx.x, lane = t & 63, w = t >> 6;
  const int l15 = lane & 15, g = lane >> 4;
  const int bid = blockIdx.x;
  const int ih = bid & 1, bq = (bid >> 1) & 7, nq = bid >> 4;
  const int b0 = bq * 4;

  for (int idx = t; idx < 64 * 192; idx += 512) {
    int cat = idx / 192, l = idx - cat * 192;
    int m = cat >> 1;
    int r = (m * l) % 192;
    float ang = (float)r * TWO_PI_OVER_L;
    float v = (cat & 1) ? -__sinf(ang) : __cosf(ang);
    Fb[cat * 200 + l] = f2bf(v);
  }

  // per-thread stage decode (row 0..127, quad 0..47)
  int srow[12], sqd[12];
#pragma unroll
  for (int j = 0; j < 12; ++j) {
    int fq = (w * 12 + j) * 64 + lane;
    srow[j] = fq / 48;
    sqd[j] = fq - srow[j] * 48;
  }
  size_t qoff[12];
#pragma unroll
  for (int j = 0; j < 12; ++j) {
    int row = srow[j];
    int b = b0 + (row >> 5), i = ih * 32 + (row & 31);
    qoff[j] = ((size_t)((b * 64 + i) * 128) ) * 192 + sqd[j] * 4;  // + n*192
  }
  __syncthreads();   // Fb ready

  for (int rep = 0; rep < REP_K1; ++rep) {
    asm volatile("" ::: "memory");
    float4 stg[12];
    // prologue: stage n0 -> qB0
    {
      const int n = nq * 4;
#pragma unroll
      for (int j = 0; j < 12; ++j)
        stg[j] = *(const float4*)(q + qoff[j] + (size_t)n * 192);
#pragma unroll
      for (int j = 0; j < 12; ++j) {
        u16x4 h; h[0] = f2bf(stg[j].x); h[1] = f2bf(stg[j].y);
        h[2] = f2bf(stg[j].z); h[3] = f2bf(stg[j].w);
        *(u16x4*)(qB0 + srow[j] * 200 + sqd[j] * 4) = h;
      }
    }
    __syncthreads();

    for (int nn = 0; nn < 4; ++nn) {
      const int n = nq * 4 + nn;
      unsigned short* cur = (nn & 1) ? qB1 : qB0;
      unsigned short* nxt = (nn & 1) ? qB0 : qB1;

      // T14: issue next phase's loads BEFORE compute
      if (nn < 3) {
#pragma unroll
        for (int j = 0; j < 12; ++j)
          stg[j] = *(const float4*)(q + qoff[j] + (size_t)(n + 1) * 192);
      }

      // MFMA from cur (bf16, single b128 A-read per kc)
      f32x4 acc[4];
#pragma unroll
      for (int a = 0; a < 4; ++a) acc[a] = zero4();
      const int row = w * 16 + l15;
#pragma unroll
      for (int kc = 0; kc < 6; ++kc) {
        short8 A = *(const short8*)(cur + row * 200 + kc * 32 + g * 8);
#pragma unroll
        for (int nt = 0; nt < 4; ++nt) {
          short8 Bf = *(const short8*)(Fb + (nt * 16 + l15) * 200 + kc * 32 + g * 8);
          acc[nt] = __builtin_amdgcn_mfma_f32_16x16x32_bf16(A, Bf, acc[nt], 0, 0, 0);
        }
      }

      // drain loads -> write other buffer
      if (nn < 3) {
#pragma unroll
        for (int j = 0; j < 12; ++j) {
          u16x4 h; h[0] = f2bf(stg[j].x); h[1] = f2bf(stg[j].y);
          h[2] = f2bf(stg[j].z); h[3] = f2bf(stg[j].w);
          *(u16x4*)(nxt + srow[j] * 200 + sqd[j] * 4) = h;
        }
      }
      __syncthreads();   // (A) nxt ready; prev XE readers done

      // C-frags -> XE (stride 132: 264B = 66 dw, bank-spread)
      const int b_loc = w >> 1, i_base = (w & 1) * 16 + g * 4;
#pragma unroll
      for (int nt = 0; nt < 4; ++nt) {
        int cat = nt * 16 + l15;
        f32x4 v = acc[nt];
#pragma unroll
        for (int r = 0; r < 4; ++r)
          XE[cat * 132 + b_loc * 32 + i_base + r] = f2bf(v[r]);
      }
      __syncthreads();   // (B) XE ready

      // XE -> Xp frag-packed stores
#pragma unroll
      for (int cc2 = 0; cc2 < 2; ++cc2) {
        int ch = cc2 * 512 + t;
        int m = ch >> 5, c = (ch >> 4) & 1, g2 = (ch >> 2) & 3, dl = ch & 3;
        short8 v = *(const short8*)(XE + (2 * m + c) * 132 + dl * 32 + g2 * 8);
        int lanep = g2 * 16 + (b0 & 15) + dl;
        int off = n * 131072 + ((((m * 2 + c) * 2 + ih) * 2 + (b0 >> 4)) * 64 + lanep) * 8;
        *(short8*)(Xp + off) = v;
      }
    }
  }
}

// ---------------------------------------------------------------------------
// k2h: complex mix, i-split staging (r9 verbatim + REP). grid 512, 512 thr,
// LDS 69888 B -> 2 blk/CU.
// ---------------------------------------------------------------------------
__global__ __launch_bounds__(512, 4)
void k2h_mix(const float* __restrict__ wr, const float* __restrict__ wi,
             const unsigned short* __restrict__ Xp, unsigned short* __restrict__ Yp) {
  extern __shared__ char smem[];
  unsigned short* T = (unsigned short*)smem;
  const int t = threadIdx.x, lane = t & 63, w = t >> 6;
  const int n = blockIdx.x >> 2, oq = blockIdx.x & 3;
  const int ol = lane & 15, il0 = (lane >> 4) * 8, g = lane >> 4;

  for (int rep = 0; rep < REP_K2; ++rep) {
    asm volatile("" ::: "memory");
    f32x4 acc[4][2][2];   // [mm][cc][Mt]
#pragma unroll
    for (int a = 0; a < 4; ++a)
#pragma unroll
      for (int c2 = 0; c2 < 2; ++c2)
#pragma unroll
        for (int b2 = 0; b2 < 2; ++b2) acc[a][c2][b2] = zero4();

    for (int ic = 0; ic < 2; ++ic) {
      if (ic + rep > 0) __syncthreads();   // T readers done before restage
#pragma unroll
      for (int jb = 0; jb < 4; ++jb) {
        float4 s[4];
#pragma unroll
        for (int k = 0; k < 4; ++k) {
          int f = (jb * 4 + k) * 512 + t;
          int mg = f & 7, o = (f >> 3) & 15, i = (f >> 7) & 31, c = (f >> 12) & 1;
          s[k] = *(const float4*)((c ? wi : wr) +
                  ((n * 64 + ic * 32 + i) * 64 + oq * 16 + o) * 32 + mg * 4);
        }
#pragma unroll
        for (int k = 0; k < 4; ++k) {
          int f = (jb * 4 + k) * 512 + t;
          int mg = f & 7, o = (f >> 3) & 15, i = (f >> 7) & 31, c = (f >> 12) & 1;
          u16x4 h; h[0] = f2bf(s[k].x); h[1] = f2bf(s[k].y); h[2] = f2bf(s[k].z); h[3] = f2bf(s[k].w);
          *(u16x4*)(T + c * 17472 + i * 546 + o * 34 + mg * 4) = h;
        }
      }
      __syncthreads();

#pragma unroll
      for (int mm = 0; mm < 4; ++mm) {
        int m = w * 4 + mm;
        const unsigned short* xb = Xp + n * 131072 + m * 4096 + ic * 1024 + lane * 8;
        short8 Ar0 = *(const short8*)(xb);
        short8 Ar1 = *(const short8*)(xb + 512);
        short8 Ai0 = *(const short8*)(xb + 2048);
        short8 Ai1 = *(const short8*)(xb + 2048 + 512);

        const unsigned short* tb = T + il0 * 546 + ol * 34 + m;
        short8 Br, Bi, nBi;
#pragma unroll
        for (int e = 0; e < 8; ++e) {
          Br[e] = (short)tb[e * 546];
          Bi[e] = (short)tb[17472 + e * 546];
          nBi[e] = Bi[e] ^ (short)0x8000;   // -Wi
        }

        acc[mm][0][0] = __builtin_amdgcn_mfma_f32_16x16x32_bf16(Ar0, Br,  acc[mm][0][0], 0, 0, 0);
        acc[mm][0][0] = __builtin_amdgcn_mfma_f32_16x16x32_bf16(Ai0, nBi, acc[mm][0][0], 0, 0, 0);
        acc[mm][0][1] = __builtin_amdgcn_mfma_f32_16x16x32_bf16(Ar1, Br,  acc[mm][0][1], 0, 0, 0);
        acc[mm][0][1] = __builtin_amdgcn_mfma_f32_16x16x32_bf16(Ai1, nBi, acc[mm][0][1], 0, 0, 0);
        acc[mm][1][0] = __builtin_amdgcn_mfma_f32_16x16x32_bf16(Ar0, Bi,  acc[mm][1][0], 0, 0, 0);
        acc[mm][1][0] = __builtin_amdgcn_mfma_f32_16x16x32_bf16(Ai0, Br,  acc[mm][1][0], 0, 0, 0);
        acc[mm][1][1] = __builtin_amdgcn_mfma_f32_16x16x32_bf16(Ar1, Bi,  acc[mm][1][1], 0, 0, 0);
        acc[mm][1][1] = __builtin_amdgcn_mfma_f32_16x16x32_bf16(Ai1, Br,  acc[mm][1][1], 0, 0, 0);
      }
    }

    // epilogue: Yp[n][b][2m+cc][oq*16+ol]
#pragma unroll
    for (int mm = 0; mm < 4; ++mm) {
      int m = w * 4 + mm;
#pragma unroll
      for (int cc = 0; cc < 2; ++cc) {
        int cat = 2 * m + cc;
#pragma unroll
        for (int Mt = 0; Mt < 2; ++Mt) {
          f32x4 v = acc[mm][cc][Mt];
#pragma unroll
          for (int r = 0; r < 4; ++r) {
            int b = Mt * 16 + g * 4 + r;
            Yp[((n * 32 + b) * 64 + cat) * 64 + oq * 16 + ol] = f2bf(v[r]);
          }
        }
      }
    }
  }
}

// ---------------------------------------------------------------------------
// K3: iDFT + transposed store (r8 verbatim, REP 6). grid 4096, 256 thr.
// ---------------------------------------------------------------------------
__global__ __launch_bounds__(256, 4)
void k3_idft(const unsigned short* __restrict__ Yp, float* __restrict__ out) {
  extern __shared__ char smem[];
  unsigned short* Yl = (unsigned short*)smem;
  float* ol = (float*)(smem + 8192);
  const int t = threadIdx.x, lane = t & 63, w = t >> 6;
  const int n = blockIdx.x & 127, b = blockIdx.x >> 7;

  for (int rep = 0; rep < REP_K3; ++rep) {
    asm volatile("" ::: "memory");
    const unsigned short* ysrc = Yp + (n * 32 + b) * 4096;
#pragma unroll
    for (int j = 0; j < 2; ++j) {
      int f = j * 256 + t;
      *(short8*)(Yl + f * 8) = *(const short8*)(ysrc + f * 8);
    }

    short8 Af[3][2];
#pragma unroll
    for (int jm = 0; jm < 3; ++jm) {
      int Mt = w + 4 * jm;
      int lt = Mt * 16 + (lane & 15);
#pragma unroll
      for (int kc = 0; kc < 2; ++kc) {
#pragma unroll
        for (int e = 0; e < 8; ++e) {
          int cat = kc * 32 + (lane >> 4) * 8 + e;
          int m = cat >> 1;
          int r = (m * lt) % 192;
          float ang = (float)r * TWO_PI_OVER_L;
          float coef = (m == 0) ? (1.0f / 192.0f) : (2.0f / 192.0f);
          float v = ((cat & 1) ? -__sinf(ang) : __cosf(ang)) * coef;
          Af[jm][kc][e] = (short)f2bf(v);
        }
      }
    }
    __syncthreads();

    f32x4 acc[3][4];
#pragma unroll
    for (int a = 0; a < 3; ++a)
#pragma unroll
      for (int bq = 0; bq < 4; ++bq) acc[a][bq] = zero4();

#pragma unroll
    for (int kc = 0; kc < 2; ++kc) {
      short8 Bf[4];
#pragma unroll
      for (int nt = 0; nt < 4; ++nt)
#pragma unroll
        for (int e = 0; e < 8; ++e) {
          int cat = kc * 32 + (lane >> 4) * 8 + e;
          Bf[nt][e] = (short)Yl[cat * 64 + nt * 16 + (lane & 15)];
        }
#pragma unroll
      for (int jm = 0; jm < 3; ++jm)
#pragma unroll
        for (int nt = 0; nt < 4; ++nt)
          acc[jm][nt] = __builtin_amdgcn_mfma_f32_16x16x32_bf16(Af[jm][kc], Bf[nt], acc[jm][nt], 0, 0, 0);
    }

#pragma unroll
    for (int jm = 0; jm < 3; ++jm) {
      int Mt = w + 4 * jm;
      int l0 = Mt * 16 + (lane >> 4) * 4;
#pragma unroll
      for (int nt = 0; nt < 4; ++nt) {
        int o = nt * 16 + (lane & 15);
        int lp = l0 ^ ((o & 7) << 2);
        *(f32x4*)(ol + o * 192 + lp) = acc[jm][nt];
      }
    }
    __syncthreads();

    float* dst = out + (b * 64 * 128 + n) * 192;
#pragma unroll
    for (int j = 0; j < 12; ++j) {
      int f = j * 256 + t;
      int o = f / 48, g2 = f - o * 48;
      int lp = g2 * 4;
      int l = lp ^ ((o & 7) << 2);
      f32x4 v = *(const f32x4*)(ol + o * 192 + lp);
      *(f32x4*)(dst + o * (128 * 192) + l) = v;
    }
    __syncthreads();
  }
}

// ---------------------------------------------------------------------------
extern "C" void kernel_launch(void* const* d_in, const int* in_sizes, int n_in,
                              void* d_out, int out_size, void* d_ws, size_t ws_size,
                              hipStream_t stream) {
  const float* q  = (const float*)d_in[0];
  const float* wr = (const float*)d_in[1];
  const float* wi = (const float*)d_in[2];
  float* out = (float*)d_out;

  unsigned short* Xp = (unsigned short*)d_ws;            // 33.5 MB
  unsigned short* Yp = Xp + 16777216;                    // 33.5 MB

  hipFuncSetAttribute((const void*)k1d_dft, hipFuncAttributeMaxDynamicSharedMemorySize, 144896);
  hipFuncSetAttribute((const void*)k2h_mix, hipFuncAttributeMaxDynamicSharedMemorySize, 69888);
  hipFuncSetAttribute((const void*)k3_idft, hipFuncAttributeMaxDynamicSharedMemorySize, 57344);

  k1d_dft<<<dim3(512), dim3(512), 144896, stream>>>(q, Xp);
  k2h_mix<<<dim3(512), dim3(512), 69888, stream>>>(wr, wi, Xp, Yp);
  k3_idft<<<dim3(4096), dim3(256), 57344, stream>>>(Yp, out);
}

// Round 11
// 173.825 us; speedup vs baseline: 5.7435x; 5.7435x over previous
//
#include <hip/hip_runtime.h>
#include <stdint.h>

// FourierBlock: B=32, D=64, N=128, L=192, M=32 modes.
// Round 11 = compose measured winners:
//   k1d: DFT with T14 async double-buffered staging (r10-measured ~62us/iter,
//        vs 97 for k1n). Bit-identical output.
//   k2i: k2f compute (r8-measured 66us/iter) + Yp layout [n][oq][b][cat][o16]
//        so every 64B line is block-private (kills the 3x RMW write
//        amplification measured on k2h: WRITE 107MB/iter for 33.5MB Yp).
//   k3:  r6-verbatim (gathers the [n][oq][b][cat][o16] layout; ~30us,
//        write-roofline).
// ws: Xp 33.5MB @0, Yp 33.5MB @16777216 u16.

typedef __attribute__((ext_vector_type(8))) short short8;
typedef __attribute__((ext_vector_type(4))) float f32x4;
typedef __attribute__((ext_vector_type(4))) unsigned short u16x4;

__device__ __forceinline__ unsigned short f2bf(float f) {
  union { float fv; uint32_t u; } v; v.fv = f;
  uint32_t u = v.u;
  u += 0x7fffu + ((u >> 16) & 1u);          // round-to-nearest-even
  return (unsigned short)(u >> 16);
}

__device__ __forceinline__ f32x4 zero4() { f32x4 z; z[0]=0.f; z[1]=0.f; z[2]=0.f; z[3]=0.f; return z; }

#define TWO_PI_OVER_L (6.283185307179586f / 192.0f)

// ---------------------------------------------------------------------------
// k1d: DFT, async double-buffered. grid 512 = (nq 32, bq 8, ih 2), 512 thr.
// LDS: qB0 [128][200]u16 @0, qB1 @51200, Fb @102400, XE [64][132] @128000.
// Per phase: issue next loads -> MFMA(cur) -> cvt->nxt -> sync -> XE -> Xp.
// ---------------------------------------------------------------------------
__global__ __launch_bounds__(512, 1)
void k1d_dft(const float* __restrict__ q, unsigned short* __restrict__ Xp) {
  extern __shared__ char smem[];
  unsigned short* qB0 = (unsigned short*)smem;
  unsigned short* qB1 = (unsigned short*)(smem + 51200);
  unsigned short* Fb  = (unsigned short*)(smem + 102400);
  unsigned short* XE  = (unsigned short*)(smem + 128000);
  const int t = threadIdx.x, lane = t & 63, w = t >> 6;
  const int l15 = lane & 15, g = lane >> 4;
  const int bid = blockIdx.x;
  const int ih = bid & 1, bq = (bid >> 1) & 7, nq = bid >> 4;
  const int b0 = bq * 4;

  for (int idx = t; idx < 64 * 192; idx += 512) {
    int cat = idx / 192, l = idx - cat * 192;
    int m = cat >> 1;
    int r = (m * l) % 192;
    float ang = (float)r * TWO_PI_OVER_L;
    float v = (cat & 1) ? -__sinf(ang) : __cosf(ang);
    Fb[cat * 200 + l] = f2bf(v);
  }

  int srow[12], sqd[12];
#pragma unroll
  for (int j = 0; j < 12; ++j) {
    int fq = (w * 12 + j) * 64 + lane;
    srow[j] = fq / 48;
    sqd[j] = fq - srow[j] * 48;
  }
  size_t qoff[12];
#pragma unroll
  for (int j = 0; j < 12; ++j) {
    int row = srow[j];
    int b = b0 + (row >> 5), i = ih * 32 + (row & 31);
    qoff[j] = ((size_t)((b * 64 + i) * 128)) * 192 + sqd[j] * 4;  // + n*192
  }
  __syncthreads();   // Fb ready

  float4 stg[12];
  // prologue: stage n0 -> qB0
  {
    const int n = nq * 4;
#pragma unroll
    for (int j = 0; j < 12; ++j)
      stg[j] = *(const float4*)(q + qoff[j] + (size_t)n * 192);
#pragma unroll
    for (int j = 0; j < 12; ++j) {
      u16x4 h; h[0] = f2bf(stg[j].x); h[1] = f2bf(stg[j].y);
      h[2] = f2bf(stg[j].z); h[3] = f2bf(stg[j].w);
      *(u16x4*)(qB0 + srow[j] * 200 + sqd[j] * 4) = h;
    }
  }
  __syncthreads();

  for (int nn = 0; nn < 4; ++nn) {
    const int n = nq * 4 + nn;
    unsigned short* cur = (nn & 1) ? qB1 : qB0;
    unsigned short* nxt = (nn & 1) ? qB0 : qB1;

    // T14: issue next phase's loads BEFORE compute
    if (nn < 3) {
#pragma unroll
      for (int j = 0; j < 12; ++j)
        stg[j] = *(const float4*)(q + qoff[j] + (size_t)(n + 1) * 192);
    }

    f32x4 acc[4];
#pragma unroll
    for (int a = 0; a < 4; ++a) acc[a] = zero4();
    const int row = w * 16 + l15;
#pragma unroll
    for (int kc = 0; kc < 6; ++kc) {
      short8 A = *(const short8*)(cur + row * 200 + kc * 32 + g * 8);
#pragma unroll
      for (int nt = 0; nt < 4; ++nt) {
        short8 Bf = *(const short8*)(Fb + (nt * 16 + l15) * 200 + kc * 32 + g * 8);
        acc[nt] = __builtin_amdgcn_mfma_f32_16x16x32_bf16(A, Bf, acc[nt], 0, 0, 0);
      }
    }

    if (nn < 3) {
#pragma unroll
      for (int j = 0; j < 12; ++j) {
        u16x4 h; h[0] = f2bf(stg[j].x); h[1] = f2bf(stg[j].y);
        h[2] = f2bf(stg[j].z); h[3] = f2bf(stg[j].w);
        *(u16x4*)(nxt + srow[j] * 200 + sqd[j] * 4) = h;
      }
    }
    __syncthreads();   // nxt ready; prev XE readers done

    const int b_loc = w >> 1, i_base = (w & 1) * 16 + g * 4;
#pragma unroll
    for (int nt = 0; nt < 4; ++nt) {
      int cat = nt * 16 + l15;
      f32x4 v = acc[nt];
#pragma unroll
      for (int r = 0; r < 4; ++r)
        XE[cat * 132 + b_loc * 32 + i_base + r] = f2bf(v[r]);
    }
    __syncthreads();   // XE ready

#pragma unroll
    for (int cc2 = 0; cc2 < 2; ++cc2) {
      int ch = cc2 * 512 + t;
      int m = ch >> 5, c = (ch >> 4) & 1, g2 = (ch >> 2) & 3, dl = ch & 3;
      short8 v = *(const short8*)(XE + (2 * m + c) * 132 + dl * 32 + g2 * 8);
      int lanep = g2 * 16 + (b0 & 15) + dl;
      int off = n * 131072 + ((((m * 2 + c) * 2 + ih) * 2 + (b0 >> 4)) * 64 + lanep) * 8;
      *(short8*)(Xp + off) = v;
    }
  }
}

// ---------------------------------------------------------------------------
// k2i: fused W-stage + complex mix (k2f compute, block-private Yp lines).
// grid 512 = (n 128, oq 4), 512 thr. LDS T 139776 B (1 blk/CU).
// Yp layout: [n][oq][b 32][cat 64][o16] -- block owns 64KB contiguous;
// each 64B line = (cat pair, o16) written by ONE wave back-to-back.
// ---------------------------------------------------------------------------
#define K2_OSTRIDE 34
#define K2_ISTRIDE 546        // 16*34 + 2
#define K2_CSTRIDE 34944      // 64*546
__global__ __launch_bounds__(512, 2)
void k2i_mix(const float* __restrict__ wr, const float* __restrict__ wi,
             const unsigned short* __restrict__ Xp, unsigned short* __restrict__ Yp) {
  extern __shared__ char smem[];
  unsigned short* T = (unsigned short*)smem;
  const int t = threadIdx.x, lane = t & 63, w = t >> 6;
  const int n = blockIdx.x >> 2, oq = blockIdx.x & 3;
  const int ol = lane & 15, il0 = (lane >> 4) * 8;

#pragma unroll
  for (int j = 0; j < 32; ++j) {
    int f = j * 512 + t;
    int mg = f & 7, o = (f >> 3) & 15, i = (f >> 7) & 63, c = (f >> 13) & 1;
    const float* src = (c ? wi : wr) + ((n * 64 + i) * 64 + oq * 16 + o) * 32 + mg * 4;
    float4 v = *(const float4*)src;
    u16x4 h; h[0] = f2bf(v.x); h[1] = f2bf(v.y); h[2] = f2bf(v.z); h[3] = f2bf(v.w);
    *(u16x4*)(T + c * K2_CSTRIDE + i * K2_ISTRIDE + o * K2_OSTRIDE + mg * 4) = h;
  }
  __syncthreads();

  unsigned short* yblk = Yp + (n * 4 + oq) * 32768;   // block-private 64KB

#pragma unroll
  for (int mm = 0; mm < 4; ++mm) {
    int m = w * 4 + mm;
    f32x4 acc[2][2];  // [cc][Mt]
#pragma unroll
    for (int a = 0; a < 2; ++a)
#pragma unroll
      for (int b2 = 0; b2 < 2; ++b2) acc[a][b2] = zero4();

#pragma unroll
    for (int ic = 0; ic < 2; ++ic) {
      const unsigned short* xb = Xp + n * 131072 + m * 4096 + ic * 1024 + lane * 8;
      short8 Ar0 = *(const short8*)(xb);
      short8 Ar1 = *(const short8*)(xb + 512);
      short8 Ai0 = *(const short8*)(xb + 2048);
      short8 Ai1 = *(const short8*)(xb + 2048 + 512);

      const unsigned short* tb = T + (ic * 32 + il0) * K2_ISTRIDE + ol * K2_OSTRIDE + m;
      short8 Br, Bi, nBi;
#pragma unroll
      for (int e = 0; e < 8; ++e) {
        Br[e] = (short)tb[e * K2_ISTRIDE];
        Bi[e] = (short)tb[K2_CSTRIDE + e * K2_ISTRIDE];
        nBi[e] = Bi[e] ^ (short)0x8000;   // -Wi
      }

      acc[0][0] = __builtin_amdgcn_mfma_f32_16x16x32_bf16(Ar0, Br,  acc[0][0], 0, 0, 0);
      acc[0][0] = __builtin_amdgcn_mfma_f32_16x16x32_bf16(Ai0, nBi, acc[0][0], 0, 0, 0);
      acc[0][1] = __builtin_amdgcn_mfma_f32_16x16x32_bf16(Ar1, Br,  acc[0][1], 0, 0, 0);
      acc[0][1] = __builtin_amdgcn_mfma_f32_16x16x32_bf16(Ai1, nBi, acc[0][1], 0, 0, 0);
      acc[1][0] = __builtin_amdgcn_mfma_f32_16x16x32_bf16(Ar0, Bi,  acc[1][0], 0, 0, 0);
      acc[1][0] = __builtin_amdgcn_mfma_f32_16x16x32_bf16(Ai0, Br,  acc[1][0], 0, 0, 0);
      acc[1][1] = __builtin_amdgcn_mfma_f32_16x16x32_bf16(Ar1, Bi,  acc[1][1], 0, 0, 0);
      acc[1][1] = __builtin_amdgcn_mfma_f32_16x16x32_bf16(Ai1, Br,  acc[1][1], 0, 0, 0);
    }

    // epilogue: Yp[n][oq][b][2m+cc][ol] -- line (cat pair) written by this wave
    const int g = lane >> 4;
#pragma unroll
    for (int Mt = 0; Mt < 2; ++Mt)
#pragma unroll
      for (int r = 0; r < 4; ++r) {
        int b = Mt * 16 + g * 4 + r;
        unsigned short* yb = yblk + b * 1024 + (2 * m) * 16 + ol;
        yb[0]  = f2bf(acc[0][Mt][r]);      // cat = 2m
        yb[16] = f2bf(acc[1][Mt][r]);      // cat = 2m+1 (same 64B line)
      }
  }
}

// ---------------------------------------------------------------------------
// K3: iDFT + transposed store (r6 VERBATIM). grid 4096 = (b 32, n 128), 256 thr.
// Stages Yp[n][oq][b][cat][o16] -> Yl[cat][66]; swizzled out-LDS; full-line out.
// ---------------------------------------------------------------------------
__global__ __launch_bounds__(256, 4)
void k3_idft(const unsigned short* __restrict__ Yp, float* __restrict__ out) {
  extern __shared__ char smem[];
  unsigned short* Yl = (unsigned short*)smem;        // [cat 64][66]
  float* ol = (float*)(smem + 8448);
  const int t = threadIdx.x, lane = t & 63, w = t >> 6;
  const int n = blockIdx.x & 127, b = blockIdx.x >> 7;

  const unsigned short* ysrc = Yp + (n * 4 * 32 + b) * 1024;   // + oq*32768
#pragma unroll
  for (int j = 0; j < 2; ++j) {
    int f = j * 256 + t;
    int og = f & 1, cat = (f >> 1) & 63, oq = f >> 7;
    short8 v = *(const short8*)(ysrc + oq * 32768 + cat * 16 + og * 8);
    unsigned int* d = (unsigned int*)(Yl + cat * 66 + oq * 16 + og * 8);
    union { short8 s; unsigned int u[4]; } uu; uu.s = v;
    d[0] = uu.u[0]; d[1] = uu.u[1]; d[2] = uu.u[2]; d[3] = uu.u[3];
  }

  short8 Af[3][2];
#pragma unroll
  for (int jm = 0; jm < 3; ++jm) {
    int Mt = w + 4 * jm;
    int lt = Mt * 16 + (lane & 15);
#pragma unroll
    for (int kc = 0; kc < 2; ++kc) {
#pragma unroll
      for (int e = 0; e < 8; ++e) {
        int cat = kc * 32 + (lane >> 4) * 8 + e;
        int m = cat >> 1;
        int r = (m * lt) % 192;
        float ang = (float)r * TWO_PI_OVER_L;
        float coef = (m == 0) ? (1.0f / 192.0f) : (2.0f / 192.0f);
        float v = ((cat & 1) ? -__sinf(ang) : __cosf(ang)) * coef;
        Af[jm][kc][e] = (short)f2bf(v);
      }
    }
  }
  __syncthreads();

  f32x4 acc[3][4];
#pragma unroll
  for (int a = 0; a < 3; ++a)
#pragma unroll
    for (int bq = 0; bq < 4; ++bq) acc[a][bq] = zero4();

#pragma unroll
  for (int kc = 0; kc < 2; ++kc) {
    short8 Bf[4];
#pragma unroll
    for (int nt = 0; nt < 4; ++nt)
#pragma unroll
      for (int e = 0; e < 8; ++e) {
        int cat = kc * 32 + (lane >> 4) * 8 + e;
        Bf[nt][e] = (short)Yl[cat * 66 + nt * 16 + (lane & 15)];
      }
#pragma unroll
    for (int jm = 0; jm < 3; ++jm)
#pragma unroll
      for (int nt = 0; nt < 4; ++nt)
        acc[jm][nt] = __builtin_amdgcn_mfma_f32_16x16x32_bf16(Af[jm][kc], Bf[nt], acc[jm][nt], 0, 0, 0);
  }

#pragma unroll
  for (int jm = 0; jm < 3; ++jm) {
    int Mt = w + 4 * jm;
    int l0 = Mt * 16 + (lane >> 4) * 4;
#pragma unroll
    for (int nt = 0; nt < 4; ++nt) {
      int o = nt * 16 + (lane & 15);
      int lp = l0 ^ ((o & 7) << 2);
      *(f32x4*)(ol + o * 192 + lp) = acc[jm][nt];
    }
  }
  __syncthreads();

  float* dst = out + (b * 64 * 128 + n) * 192;
#pragma unroll
  for (int j = 0; j < 12; ++j) {
    int f = j * 256 + t;
    int o = f / 48, g2 = f - o * 48;
    int lp = g2 * 4;
    int l = lp ^ ((o & 7) << 2);
    f32x4 v = *(const f32x4*)(ol + o * 192 + lp);
    *(f32x4*)(dst + o * (128 * 192) + l) = v;
  }
}

// ---------------------------------------------------------------------------
extern "C" void kernel_launch(void* const* d_in, const int* in_sizes, int n_in,
                              void* d_out, int out_size, void* d_ws, size_t ws_size,
                              hipStream_t stream) {
  const float* q  = (const float*)d_in[0];
  const float* wr = (const float*)d_in[1];
  const float* wi = (const float*)d_in[2];
  float* out = (float*)d_out;

  unsigned short* Xp = (unsigned short*)d_ws;            // 33.5 MB
  unsigned short* Yp = Xp + 16777216;                    // 33.5 MB

  hipFuncSetAttribute((const void*)k1d_dft, hipFuncAttributeMaxDynamicSharedMemorySize, 144896);
  hipFuncSetAttribute((const void*)k2i_mix, hipFuncAttributeMaxDynamicSharedMemorySize, 139776);
  hipFuncSetAttribute((const void*)k3_idft, hipFuncAttributeMaxDynamicSharedMemorySize, 57600);

  k1d_dft<<<dim3(512), dim3(512), 144896, stream>>>(q, Xp);
  k2i_mix<<<dim3(512), dim3(512), 139776, stream>>>(wr, wi, Xp, Yp);
  k3_idft<<<dim3(4096), dim3(256), 57600, stream>>>(Yp, out);
}